// Round 1
// baseline (1536.087 us; speedup 1.0000x reference)
//
#include <hip/hip_runtime.h>

#define N_USERC 100000
#define N_ITEMC 50000
#define N_TOTALC 150000
#define DC 64
#define NNZ_AC 2000000
#define NNZ_SC 1000000
#define N_TAILC 10000
#define N_HEADC 4000
#define TOPKC 10
#define BATCHC 4096
#define N_NEGC 4
#define CONVF 40.0f

// ---------------- CSR build ----------------
__global__ void hist_kernel(const int* __restrict__ rows, int n, int* __restrict__ counts) {
    int i = blockIdx.x * blockDim.x + threadIdx.x;
    if (i < n) atomicAdd(&counts[rows[i]], 1);
}

// 2048 elements per block (256 threads x 8)
__global__ __launch_bounds__(256) void scan_p1(const int* __restrict__ in, int n,
                                               int* __restrict__ out, int* __restrict__ bsums) {
    __shared__ int lds[256];
    int tid = threadIdx.x;
    int base = blockIdx.x * 2048 + tid * 8;
    int v[8];
    int s = 0;
#pragma unroll
    for (int k = 0; k < 8; ++k) {
        int idx = base + k;
        v[k] = s;
        s += (idx < n) ? in[idx] : 0;
    }
    lds[tid] = s;
    __syncthreads();
    for (int off = 1; off < 256; off <<= 1) {
        int t = (tid >= off) ? lds[tid - off] : 0;
        __syncthreads();
        lds[tid] += t;
        __syncthreads();
    }
    int texcl = (tid > 0) ? lds[tid - 1] : 0;
#pragma unroll
    for (int k = 0; k < 8; ++k) {
        int idx = base + k;
        if (idx < n) out[idx] = texcl + v[k];
    }
    if (tid == 255) bsums[blockIdx.x] = lds[255];
}

__global__ void scan_p2(int* __restrict__ bsums, int nb) {
    if (threadIdx.x == 0 && blockIdx.x == 0) {
        int s = 0;
        for (int i = 0; i < nb; ++i) { int t = bsums[i]; bsums[i] = s; s += t; }
    }
}

__global__ void scan_p3(int* __restrict__ out, int n, const int* __restrict__ bsums,
                        int* __restrict__ cursor, int total) {
    int i = blockIdx.x * blockDim.x + threadIdx.x;
    if (i < n) {
        int val = out[i] + bsums[i >> 11];
        out[i] = val;
        cursor[i] = val;
    }
    if (i == 0) out[n] = total;
}

__global__ void scatter_kernel(const float* __restrict__ vals, const int* __restrict__ rows,
                               const int* __restrict__ cols, int n, int* __restrict__ cursor,
                               float* __restrict__ svals, int* __restrict__ scols) {
    int i = blockIdx.x * blockDim.x + threadIdx.x;
    if (i < n) {
        int p = atomicAdd(&cursor[rows[i]], 1);
        svals[p] = vals[i];
        scols[p] = cols[i];
    }
}

// ---------------- CSR SpMM: one wave per row, lane = feature dim ----------------
__global__ __launch_bounds__(256) void spmm_csr(const int* __restrict__ rowptr,
                                                const float* __restrict__ vals,
                                                const int* __restrict__ cols,
                                                const float* __restrict__ x,
                                                float* __restrict__ y, int nrows) {
    int w = (blockIdx.x * blockDim.x + threadIdx.x) >> 6;
    int lane = threadIdx.x & 63;
    if (w >= nrows) return;
    int s = rowptr[w], e = rowptr[w + 1];
    float a0 = 0.f, a1 = 0.f, a2 = 0.f, a3 = 0.f;
    int j = s;
    for (; j + 4 <= e; j += 4) {
        float v0 = vals[j], v1 = vals[j + 1], v2 = vals[j + 2], v3 = vals[j + 3];
        int c0 = cols[j], c1 = cols[j + 1], c2 = cols[j + 2], c3 = cols[j + 3];
        a0 += v0 * x[c0 * 64 + lane];
        a1 += v1 * x[c1 * 64 + lane];
        a2 += v2 * x[c2 * 64 + lane];
        a3 += v3 * x[c3 * 64 + lane];
    }
    for (; j < e; ++j) a0 += vals[j] * x[cols[j] * 64 + lane];
    y[w * 64 + lane] = a0 + a1 + a2 + a3;
}

// ---------------- MLP encoder: one wave per row ----------------
__global__ __launch_bounds__(256) void enc_kernel(const float* __restrict__ emb, const int* __restrict__ idx,
                                                  const float* __restrict__ w0, const float* __restrict__ b0,
                                                  const float* __restrict__ w2, const float* __restrict__ b2,
                                                  float* __restrict__ out) {
    __shared__ float fsh[4][64];
    __shared__ float hsh[4][256];
    int wv = threadIdx.x >> 6, lane = threadIdx.x & 63;
    int r = blockIdx.x * 4 + wv;
    int item = idx[r];
    fsh[wv][lane] = emb[item * 64 + lane];
    __syncthreads();
#pragma unroll
    for (int q = 0; q < 4; ++q) {
        int j = q * 64 + lane;
        float acc = b0[j];
#pragma unroll
        for (int d4 = 0; d4 < 64; d4 += 4) {
            float4 wv4 = *(const float4*)&w0[j * 64 + d4];
            acc += wv4.x * fsh[wv][d4] + wv4.y * fsh[wv][d4 + 1] + wv4.z * fsh[wv][d4 + 2] + wv4.w * fsh[wv][d4 + 3];
        }
        hsh[wv][j] = acc;
    }
    __syncthreads();
    float acc = b2[lane];
#pragma unroll
    for (int k4 = 0; k4 < 256; k4 += 4) {
        float4 wv4 = *(const float4*)&w2[lane * 256 + k4];
        acc += wv4.x * hsh[wv][k4] + wv4.y * hsh[wv][k4 + 1] + wv4.z * hsh[wv][k4 + 2] + wv4.w * hsh[wv][k4 + 3];
    }
    out[r * 64 + lane] = acc;
}

// ---------------- fused scores + top-k ----------------
// block = 256 threads = 16 teams x 16 members; 16 tail rows per block
__global__ __launch_bounds__(256) void topk_kernel(const float* __restrict__ tail_e, const float* __restrict__ top_e,
                                                   const int* __restrict__ head_idx,
                                                   int* __restrict__ ig_cols, float* __restrict__ ig_vals) {
    __shared__ float tailv[16][68];
    __shared__ float ldsH[128][68];
    int tid = threadIdx.x;
    int rowbase = blockIdx.x * 16;
    for (int idx = tid; idx < 16 * 16; idx += 256) {
        int r = idx >> 4, d4 = (idx & 15) << 2;
        *(float4*)&tailv[r][d4] = *(const float4*)&tail_e[(rowbase + r) * 64 + d4];
    }
    int tr = tid >> 4, tm = tid & 15;
    float v[TOPKC];
    int hid[TOPKC];
#pragma unroll
    for (int k = 0; k < TOPKC; ++k) { v[k] = -1e30f; hid[k] = -1; }

    for (int t0 = 0; t0 < N_HEADC; t0 += 128) {
        __syncthreads();
        for (int idx = tid; idx < 128 * 16; idx += 256) {
            int h = idx >> 4, d4 = (idx & 15) << 2;
            float4 val;
            if (t0 + h < N_HEADC) val = *(const float4*)&top_e[(t0 + h) * 64 + d4];
            else val = make_float4(0.f, 0.f, 0.f, 0.f);
            *(float4*)&ldsH[h][d4] = val;
        }
        __syncthreads();
        float acc[8];
#pragma unroll
        for (int jj = 0; jj < 8; ++jj) acc[jj] = 0.f;
#pragma unroll 4
        for (int d4 = 0; d4 < 64; d4 += 4) {
            float4 tv = *(const float4*)&tailv[tr][d4];
#pragma unroll
            for (int jj = 0; jj < 8; ++jj) {
                int h = jj * 16 + tm;
                float4 hv = *(const float4*)&ldsH[h][d4];
                acc[jj] += tv.x * hv.x + tv.y * hv.y + tv.z * hv.z + tv.w * hv.w;
            }
        }
#pragma unroll
        for (int jj = 0; jj < 8; ++jj) {
            int hg = t0 + jj * 16 + tm;
            float sc = acc[jj];
            if (hg < N_HEADC && sc > v[TOPKC - 1]) {
                float cv = sc; int ci = hg;
#pragma unroll
                for (int k = 0; k < TOPKC; ++k) {
                    if (cv > v[k]) { float tv_ = v[k]; int ti = hid[k]; v[k] = cv; hid[k] = ci; cv = tv_; ci = ti; }
                }
            }
        }
    }
    // team merge: 10 extraction rounds across 16 members
    int ptr = 0;
    float ssum = 0.f;
    float outv = 0.f;
    int outid = -1;
#pragma unroll
    for (int r = 0; r < TOPKC; ++r) {
        float cv = (ptr < TOPKC) ? v[ptr] : -1e30f;
        int ci = (ptr < TOPKC) ? hid[ptr] : -1;
        int wl = tm;
#pragma unroll
        for (int m = 1; m < 16; m <<= 1) {
            float ov = __shfl_xor(cv, m, 64);
            int oi = __shfl_xor(ci, m, 64);
            int ol = __shfl_xor(wl, m, 64);
            if (ov > cv || (ov == cv && ol < wl)) { cv = ov; ci = oi; wl = ol; }
        }
        if (wl == tm) ptr++;
        ssum += 1.f / (1.f + expf(-cv));
        if (tm == r) { outv = cv; outid = ci; }
    }
    if (tm < TOPKC) {
        float s = 1.f / (1.f + expf(-outv));
        float w = s / (ssum + 1.f);
        int row = rowbase + tr;
        ig_vals[row * TOPKC + tm] = w;
        ig_cols[row * TOPKC + tm] = head_idx[outid];
    }
}

// ---------------- item_enh accumulation: one wave per ig entry ----------------
__global__ __launch_bounds__(256) void ig_spmm_kernel(const int* __restrict__ tail_idx,
                                                      const int* __restrict__ ig_cols,
                                                      const float* __restrict__ ig_vals,
                                                      const float* __restrict__ items,
                                                      float* __restrict__ enh) {
    int e = (blockIdx.x * blockDim.x + threadIdx.x) >> 6;
    int lane = threadIdx.x & 63;
    if (e >= N_TAILC * TOPKC) return;
    int row = tail_idx[e / TOPKC];
    int col = ig_cols[e];
    float w = ig_vals[e];
    atomicAdd(&enh[row * 64 + lane], w * items[col * 64 + lane]);
}

// ---------------- final loss: one wave per batch sample ----------------
__global__ __launch_bounds__(256) void loss_kernel(const float* __restrict__ u0, const float* __restrict__ u1,
                                                   const float* __restrict__ u2, const float* __restrict__ items,
                                                   const float* __restrict__ enh, const float* __restrict__ deg,
                                                   const float* __restrict__ user_emb, const float* __restrict__ item_emb,
                                                   const int* __restrict__ bu, const int* __restrict__ bp,
                                                   const int* __restrict__ bn, float* __restrict__ out) {
    int w = (blockIdx.x * blockDim.x + threadIdx.x) >> 6;
    int lane = threadIdx.x & 63;
    if (w >= BATCHC) return;
    int uu = bu[w], pp = bp[w];
    float ue = (u0[uu * 64 + lane] + u1[uu * 64 + lane] + u2[uu * 64 + lane]) * (1.f / 3.f);
    float swp = CONVF / (CONVF + expf(deg[pp] * (1.f / CONVF)));
    float pe = items[pp * 64 + lane] + swp * enh[pp * 64 + lane];
    float ps = ue * pe;
    float ns = 0.f;
    float u0e = user_emb[uu * 64 + lane];
    float p0e = item_emb[pp * 64 + lane];
    float reg = u0e * u0e + p0e * p0e;
#pragma unroll
    for (int k = 0; k < N_NEGC; ++k) {
        int nn = bn[w * N_NEGC + k];
        float swn = CONVF / (CONVF + expf(deg[nn] * (1.f / CONVF)));
        float nv = items[nn * 64 + lane] + swn * enh[nn * 64 + lane];
        ns += ue * nv;
        float n0 = item_emb[nn * 64 + lane];
        reg += n0 * n0;
    }
#pragma unroll
    for (int m = 32; m >= 1; m >>= 1) {
        ps += __shfl_xor(ps, m, 64);
        ns += __shfl_xor(ns, m, 64);
        reg += __shfl_xor(reg, m, 64);
    }
    if (lane == 0) {
        float x = ns * (1.f / N_NEGC) - ps;
        float sp = (x > 0.f) ? (x + log1pf(expf(-x))) : log1pf(expf(x));
        atomicAdd(&out[0], sp * (1.f / BATCHC));
        atomicAdd(&out[1], 0.5f * reg * (1.f / BATCHC));
    }
}

extern "C" void kernel_launch(void* const* d_in, const int* in_sizes, int n_in,
                              void* d_out, int out_size, void* d_ws, size_t ws_size,
                              hipStream_t stream) {
    const float* user_emb = (const float*)d_in[0];
    const float* item_emb = (const float*)d_in[1];
    const float* w0 = (const float*)d_in[2];
    const float* b0 = (const float*)d_in[3];
    const float* w2 = (const float*)d_in[4];
    const float* b2 = (const float*)d_in[5];
    const float* a_vals = (const float*)d_in[6];
    const float* s_vals = (const float*)d_in[7];
    const float* item_degree = (const float*)d_in[8];
    const int* a_rows = (const int*)d_in[9];
    const int* a_cols = (const int*)d_in[10];
    const int* s_rows = (const int*)d_in[11];
    const int* s_cols = (const int*)d_in[12];
    const int* tail_idx = (const int*)d_in[13];
    const int* head_idx = (const int*)d_in[14];
    const int* batch_user = (const int*)d_in[15];
    const int* batch_pos = (const int*)d_in[16];
    const int* batch_neg = (const int*)d_in[17];
    float* out = (float*)d_out;

    // ---- workspace carve (all 256B aligned) ----
    char* p = (char*)d_ws;
    auto carve = [&](size_t bytes) -> void* {
        void* r = (void*)p;
        p += (bytes + 255) & ~size_t(255);
        return r;
    };
    float* embA = (float*)carve((size_t)N_TOTALC * 64 * 4);
    float* embB = (float*)carve((size_t)N_TOTALC * 64 * 4);
    float* u1 = (float*)carve((size_t)N_USERC * 64 * 4);
    float* u2 = (float*)carve((size_t)N_USERC * 64 * 4);
    float* enh = (float*)carve((size_t)N_ITEMC * 64 * 4);
    float* tail_e = (float*)carve((size_t)N_TAILC * 64 * 4);
    float* top_e = (float*)carve((size_t)N_HEADC * 64 * 4);
    float* a_svals = (float*)carve((size_t)NNZ_AC * 4);
    int* a_scols = (int*)carve((size_t)NNZ_AC * 4);
    float* s_svals = (float*)carve((size_t)NNZ_SC * 4);
    int* s_scols = (int*)carve((size_t)NNZ_SC * 4);
    int* a_rowptr = (int*)carve((size_t)(N_TOTALC + 1) * 4);
    int* a_cursor = (int*)carve((size_t)N_TOTALC * 4);
    int* s_rowptr = (int*)carve((size_t)(N_USERC + 1) * 4);
    int* s_cursor = (int*)carve((size_t)N_USERC * 4);
    int* bsums = (int*)carve(128 * 4);
    int* ig_cols_buf = (int*)carve((size_t)N_TAILC * TOPKC * 4);
    float* ig_vals_buf = (float*)carve((size_t)N_TAILC * TOPKC * 4);

    // ---- CSR build for A (150000 rows, 2M nnz) ----
    hipMemsetAsync(a_cursor, 0, (size_t)N_TOTALC * 4, stream);
    hist_kernel<<<(NNZ_AC + 255) / 256, 256, 0, stream>>>(a_rows, NNZ_AC, a_cursor);
    {
        int nb = (N_TOTALC + 2047) / 2048;
        scan_p1<<<nb, 256, 0, stream>>>(a_cursor, N_TOTALC, a_rowptr, bsums);
        scan_p2<<<1, 64, 0, stream>>>(bsums, nb);
        scan_p3<<<(N_TOTALC + 255) / 256, 256, 0, stream>>>(a_rowptr, N_TOTALC, bsums, a_cursor, NNZ_AC);
    }
    scatter_kernel<<<(NNZ_AC + 255) / 256, 256, 0, stream>>>(a_vals, a_rows, a_cols, NNZ_AC, a_cursor, a_svals, a_scols);

    // ---- CSR build for S (100000 rows, 1M nnz) ----
    hipMemsetAsync(s_cursor, 0, (size_t)N_USERC * 4, stream);
    hist_kernel<<<(NNZ_SC + 255) / 256, 256, 0, stream>>>(s_rows, NNZ_SC, s_cursor);
    {
        int nb = (N_USERC + 2047) / 2048;
        scan_p1<<<nb, 256, 0, stream>>>(s_cursor, N_USERC, s_rowptr, bsums);
        scan_p2<<<1, 64, 0, stream>>>(bsums, nb);
        scan_p3<<<(N_USERC + 255) / 256, 256, 0, stream>>>(s_rowptr, N_USERC, bsums, s_cursor, NNZ_SC);
    }
    scatter_kernel<<<(NNZ_SC + 255) / 256, 256, 0, stream>>>(s_vals, s_rows, s_cols, NNZ_SC, s_cursor, s_svals, s_scols);

    // ---- encoder + top-k (independent of graph conv; uses original item_emb) ----
    enc_kernel<<<N_TAILC / 4, 256, 0, stream>>>(item_emb, tail_idx, w0, b0, w2, b2, tail_e);
    enc_kernel<<<N_HEADC / 4, 256, 0, stream>>>(item_emb, head_idx, w0, b0, w2, b2, top_e);
    topk_kernel<<<N_TAILC / 16, 256, 0, stream>>>(tail_e, top_e, head_idx, ig_cols_buf, ig_vals_buf);

    // ---- all_emb = concat(user_emb, item_emb); 3 A-layers ping-pong ----
    hipMemcpyAsync(embA, user_emb, (size_t)N_USERC * 64 * 4, hipMemcpyDeviceToDevice, stream);
    hipMemcpyAsync(embA + (size_t)N_USERC * 64, item_emb, (size_t)N_ITEMC * 64 * 4, hipMemcpyDeviceToDevice, stream);
    {
        int blocks = (N_TOTALC + 3) / 4;
        spmm_csr<<<blocks, 256, 0, stream>>>(a_rowptr, a_svals, a_scols, embA, embB, N_TOTALC);
        spmm_csr<<<blocks, 256, 0, stream>>>(a_rowptr, a_svals, a_scols, embB, embA, N_TOTALC);
        spmm_csr<<<blocks, 256, 0, stream>>>(a_rowptr, a_svals, a_scols, embA, embB, N_TOTALC);
    }
    // final all_emb is in embB: users = embB[0:NU], items = embB[NU:]
    const float* u0 = embB;
    const float* items = embB + (size_t)N_USERC * 64;

    // ---- 2 S-layers on users ----
    {
        int blocks = (N_USERC + 3) / 4;
        spmm_csr<<<blocks, 256, 0, stream>>>(s_rowptr, s_svals, s_scols, u0, u1, N_USERC);
        spmm_csr<<<blocks, 256, 0, stream>>>(s_rowptr, s_svals, s_scols, u1, u2, N_USERC);
    }

    // ---- item enhancement ----
    hipMemsetAsync(enh, 0, (size_t)N_ITEMC * 64 * 4, stream);
    ig_spmm_kernel<<<(N_TAILC * TOPKC) / 4, 256, 0, stream>>>(tail_idx, ig_cols_buf, ig_vals_buf, items, enh);

    // ---- loss + reg ----
    hipMemsetAsync(out, 0, 2 * sizeof(float), stream);
    loss_kernel<<<BATCHC / 4, 256, 0, stream>>>(u0, u1, u2, items, enh, item_degree,
                                                user_emb, item_emb, batch_user, batch_pos, batch_neg, out);
}

// Round 2
// 1428.387 us; speedup vs baseline: 1.0754x; 1.0754x over previous
//
#include <hip/hip_runtime.h>

#define N_USERC 100000
#define N_ITEMC 50000
#define N_TOTALC 150000
#define DC 64
#define NNZ_AC 2000000
#define NNZ_SC 1000000
#define N_TAILC 10000
#define N_HEADC 4000
#define TOPKC 10
#define BATCHC 4096
#define N_NEGC 4
#define CONVF 40.0f
#define CHUNK_ROWS 2048

// ---------------- CSR build ----------------
__global__ void hist_kernel(const int* __restrict__ rows, int n, int* __restrict__ counts) {
    int i = blockIdx.x * blockDim.x + threadIdx.x;
    if (i < n) atomicAdd(&counts[rows[i]], 1);
}

// 2048 elements per block (256 threads x 8)
__global__ __launch_bounds__(256) void scan_p1(const int* __restrict__ in, int n,
                                               int* __restrict__ out, int* __restrict__ bsums) {
    __shared__ int lds[256];
    int tid = threadIdx.x;
    int base = blockIdx.x * 2048 + tid * 8;
    int v[8];
    int s = 0;
#pragma unroll
    for (int k = 0; k < 8; ++k) {
        int idx = base + k;
        v[k] = s;
        s += (idx < n) ? in[idx] : 0;
    }
    lds[tid] = s;
    __syncthreads();
    for (int off = 1; off < 256; off <<= 1) {
        int t = (tid >= off) ? lds[tid - off] : 0;
        __syncthreads();
        lds[tid] += t;
        __syncthreads();
    }
    int texcl = (tid > 0) ? lds[tid - 1] : 0;
#pragma unroll
    for (int k = 0; k < 8; ++k) {
        int idx = base + k;
        if (idx < n) out[idx] = texcl + v[k];
    }
    if (tid == 255) bsums[blockIdx.x] = lds[255];
}

__global__ void scan_p2(int* __restrict__ bsums, int nb) {
    if (threadIdx.x == 0 && blockIdx.x == 0) {
        int s = 0;
        for (int i = 0; i < nb; ++i) { int t = bsums[i]; bsums[i] = s; s += t; }
    }
}

__global__ void scan_p3(int* __restrict__ out, int n, const int* __restrict__ bsums,
                        int* __restrict__ cursor, int total) {
    int i = blockIdx.x * blockDim.x + threadIdx.x;
    if (i < n) {
        int val = out[i] + bsums[i >> 11];
        out[i] = val;
        cursor[i] = val;
    }
    if (i == 0) out[n] = total;
}

__global__ void scatter_kernel(const float* __restrict__ vals, const int* __restrict__ rows,
                               const int* __restrict__ cols, int n, int* __restrict__ cursor,
                               float* __restrict__ svals, int* __restrict__ scols) {
    int i = blockIdx.x * blockDim.x + threadIdx.x;
    if (i < n) {
        int p = atomicAdd(&cursor[rows[i]], 1);
        svals[p] = vals[i];
        scols[p] = cols[i];
    }
}

// ---------------- CSR SpMM: one wave per row, lane = feature dim ----------------
__global__ __launch_bounds__(256) void spmm_csr(const int* __restrict__ rowptr,
                                                const float* __restrict__ vals,
                                                const int* __restrict__ cols,
                                                const float* __restrict__ x,
                                                float* __restrict__ y, int nrows) {
    int w = (blockIdx.x * blockDim.x + threadIdx.x) >> 6;
    int lane = threadIdx.x & 63;
    if (w >= nrows) return;
    int s = rowptr[w], e = rowptr[w + 1];
    float a0 = 0.f, a1 = 0.f, a2 = 0.f, a3 = 0.f;
    int j = s;
    for (; j + 4 <= e; j += 4) {
        float v0 = vals[j], v1 = vals[j + 1], v2 = vals[j + 2], v3 = vals[j + 3];
        int c0 = cols[j], c1 = cols[j + 1], c2 = cols[j + 2], c3 = cols[j + 3];
        a0 += v0 * x[c0 * 64 + lane];
        a1 += v1 * x[c1 * 64 + lane];
        a2 += v2 * x[c2 * 64 + lane];
        a3 += v3 * x[c3 * 64 + lane];
    }
    for (; j < e; ++j) a0 += vals[j] * x[cols[j] * 64 + lane];
    y[w * 64 + lane] = a0 + a1 + a2 + a3;
}

// ---------------- collapsed encoder: Mrm[j][d] = sum_k w2[j,k]*w0[k,d]; cvec = w2@b0 + b2 ----------------
__global__ __launch_bounds__(256) void mc_kernel(const float* __restrict__ w0, const float* __restrict__ b0,
                                                 const float* __restrict__ w2, const float* __restrict__ b2,
                                                 float* __restrict__ Mrm, float* __restrict__ cvec) {
    int idx = blockIdx.x * 256 + threadIdx.x;
    if (idx < 4096) {
        int j = idx >> 6, d = idx & 63;
        float acc = 0.f;
        for (int k = 0; k < 256; ++k) acc += w2[j * 256 + k] * w0[k * 64 + d];
        Mrm[idx] = acc;
    } else if (idx < 4160) {
        int i = idx - 4096;
        float acc = b2[i];
        for (int k = 0; k < 256; ++k) acc += w2[i * 256 + k] * b0[k];
        cvec[i] = acc;
    }
}

// enc(f) = f @ Mrm^T + cvec ; one wave per row
__global__ __launch_bounds__(256) void enc2_kernel(const float* __restrict__ emb, const int* __restrict__ idx,
                                                   const float* __restrict__ Mrm, const float* __restrict__ cvec,
                                                   float* __restrict__ out, int n) {
    __shared__ float fsh[4][64];
    int wv = threadIdx.x >> 6, lane = threadIdx.x & 63;
    int r = blockIdx.x * 4 + wv;
    if (r < n) fsh[wv][lane] = emb[(size_t)idx[r] * 64 + lane];
    __syncthreads();
    if (r >= n) return;
    float acc = cvec[lane];
#pragma unroll
    for (int d4 = 0; d4 < 64; d4 += 4) {
        float4 m4 = *(const float4*)&Mrm[lane * 64 + d4];   // 16KB table, L1-resident
        float4 f4 = *(const float4*)&fsh[wv][d4];            // broadcast
        acc += m4.x * f4.x + m4.y * f4.y + m4.z * f4.z + m4.w * f4.w;
    }
    out[(size_t)r * 64 + lane] = acc;
}

// ---------------- score GEMM: C[m x 4000] = A[m x 64] @ B[4000 x 64]^T ----------------
// block tile 128x128, thread tile 8x8, strided lane mapping (rows ty+16i, cols tx+16j)
__global__ __launch_bounds__(256) void score_gemm(const float* __restrict__ A,
                                                  const float* __restrict__ B,
                                                  float* __restrict__ C, int M) {
    __shared__ float As[32][132];   // As[k][row]
    __shared__ float Bs[32][132];   // Bs[k][col]
    int tid = threadIdx.x;
    int tx = tid & 15, ty = tid >> 4;
    int rowbase = blockIdx.y * 128;
    int colbase = blockIdx.x * 128;
    float acc[8][8];
#pragma unroll
    for (int i = 0; i < 8; ++i)
#pragma unroll
        for (int j = 0; j < 8; ++j) acc[i][j] = 0.f;

    for (int k0 = 0; k0 < 64; k0 += 32) {
        __syncthreads();
#pragma unroll
        for (int i = 0; i < 4; ++i) {
            int f = tid + i * 256;        // 0..1023
            int r = f >> 3;               // 0..127
            int kq = (f & 7) << 2;        // 0,4,...,28
            int grow = rowbase + r;
            float4 av = (grow < M) ? *(const float4*)&A[(size_t)grow * 64 + k0 + kq]
                                   : make_float4(0.f, 0.f, 0.f, 0.f);
            As[kq + 0][r] = av.x; As[kq + 1][r] = av.y; As[kq + 2][r] = av.z; As[kq + 3][r] = av.w;
            int gcol = colbase + r;
            float4 bv = (gcol < N_HEADC) ? *(const float4*)&B[(size_t)gcol * 64 + k0 + kq]
                                         : make_float4(0.f, 0.f, 0.f, 0.f);
            Bs[kq + 0][r] = bv.x; Bs[kq + 1][r] = bv.y; Bs[kq + 2][r] = bv.z; Bs[kq + 3][r] = bv.w;
        }
        __syncthreads();
#pragma unroll
        for (int k = 0; k < 32; ++k) {
            float a[8], b[8];
#pragma unroll
            for (int i = 0; i < 8; ++i) a[i] = As[k][ty + 16 * i];
#pragma unroll
            for (int j = 0; j < 8; ++j) b[j] = Bs[k][tx + 16 * j];
#pragma unroll
            for (int i = 0; i < 8; ++i)
#pragma unroll
                for (int j = 0; j < 8; ++j) acc[i][j] += a[i] * b[j];
        }
    }
#pragma unroll
    for (int i = 0; i < 8; ++i) {
        int r = rowbase + ty + 16 * i;
        if (r < M) {
#pragma unroll
            for (int j = 0; j < 8; ++j) {
                int c = colbase + tx + 16 * j;
                if (c < N_HEADC) C[(size_t)r * N_HEADC + c] = acc[i][j];
            }
        }
    }
}

// ---------------- per-row top-k on materialized scores: one wave per row ----------------
__global__ __launch_bounds__(256) void topk_rows(const float* __restrict__ scores, int nrows, int row0,
                                                 const int* __restrict__ head_idx,
                                                 int* __restrict__ ig_cols, float* __restrict__ ig_vals) {
    int w = (blockIdx.x * blockDim.x + threadIdx.x) >> 6;
    int lane = threadIdx.x & 63;
    if (w >= nrows) return;
    const float* srow = scores + (size_t)w * N_HEADC;
    float v[TOPKC];
    int id[TOPKC];
#pragma unroll
    for (int k = 0; k < TOPKC; ++k) { v[k] = -1e30f; id[k] = -1; }
    // 4000 floats = 1000 float4; lanes stride 64
    for (int it = 0; it < 16; ++it) {
        int f4 = lane + it * 64;
        if (f4 < 1000) {
            float4 s4 = ((const float4*)srow)[f4];
            int cb = f4 * 4;
            float vv[4] = { s4.x, s4.y, s4.z, s4.w };
#pragma unroll
            for (int q = 0; q < 4; ++q) {
                float sc = vv[q];
                if (sc > v[TOPKC - 1]) {
                    float cv = sc; int ci = cb + q;
#pragma unroll
                    for (int k = 0; k < TOPKC; ++k) {
                        if (cv > v[k]) { float t = v[k]; int ti = id[k]; v[k] = cv; id[k] = ci; cv = t; ci = ti; }
                    }
                }
            }
        }
    }
    // 64-lane butterfly extraction of global top-10
    int ptr = 0;
    float ssum = 0.f;
    float outv = 0.f;
    int outid = -1;
#pragma unroll
    for (int r = 0; r < TOPKC; ++r) {
        float cv = (ptr < TOPKC) ? v[ptr] : -1e30f;
        int ci = (ptr < TOPKC) ? id[ptr] : -1;
        int wl = lane;
#pragma unroll
        for (int m = 1; m < 64; m <<= 1) {
            float ov = __shfl_xor(cv, m, 64);
            int oi = __shfl_xor(ci, m, 64);
            int ol = __shfl_xor(wl, m, 64);
            if (ov > cv || (ov == cv && ol < wl)) { cv = ov; ci = oi; wl = ol; }
        }
        if (wl == lane) ptr++;
        ssum += 1.f / (1.f + expf(-cv));
        if (lane == r) { outv = cv; outid = ci; }
    }
    if (lane < TOPKC) {
        float s = 1.f / (1.f + expf(-outv));
        float wgt = s / (ssum + 1.f);
        int grow = row0 + w;
        ig_vals[grow * TOPKC + lane] = wgt;
        ig_cols[grow * TOPKC + lane] = head_idx[outid];
    }
}

// ---------------- item_enh accumulation: one wave per ig entry ----------------
__global__ __launch_bounds__(256) void ig_spmm_kernel(const int* __restrict__ tail_idx,
                                                      const int* __restrict__ ig_cols,
                                                      const float* __restrict__ ig_vals,
                                                      const float* __restrict__ items,
                                                      float* __restrict__ enh) {
    int e = (blockIdx.x * blockDim.x + threadIdx.x) >> 6;
    int lane = threadIdx.x & 63;
    if (e >= N_TAILC * TOPKC) return;
    int row = tail_idx[e / TOPKC];
    int col = ig_cols[e];
    float w = ig_vals[e];
    atomicAdd(&enh[row * 64 + lane], w * items[col * 64 + lane]);
}

// ---------------- final loss: one wave per batch sample ----------------
__global__ __launch_bounds__(256) void loss_kernel(const float* __restrict__ u0, const float* __restrict__ u1,
                                                   const float* __restrict__ u2, const float* __restrict__ items,
                                                   const float* __restrict__ enh, const float* __restrict__ deg,
                                                   const float* __restrict__ user_emb, const float* __restrict__ item_emb,
                                                   const int* __restrict__ bu, const int* __restrict__ bp,
                                                   const int* __restrict__ bn, float* __restrict__ out) {
    int w = (blockIdx.x * blockDim.x + threadIdx.x) >> 6;
    int lane = threadIdx.x & 63;
    if (w >= BATCHC) return;
    int uu = bu[w], pp = bp[w];
    float ue = (u0[uu * 64 + lane] + u1[uu * 64 + lane] + u2[uu * 64 + lane]) * (1.f / 3.f);
    float swp = CONVF / (CONVF + expf(deg[pp] * (1.f / CONVF)));
    float pe = items[pp * 64 + lane] + swp * enh[pp * 64 + lane];
    float ps = ue * pe;
    float ns = 0.f;
    float u0e = user_emb[uu * 64 + lane];
    float p0e = item_emb[pp * 64 + lane];
    float reg = u0e * u0e + p0e * p0e;
#pragma unroll
    for (int k = 0; k < N_NEGC; ++k) {
        int nn = bn[w * N_NEGC + k];
        float swn = CONVF / (CONVF + expf(deg[nn] * (1.f / CONVF)));
        float nv = items[nn * 64 + lane] + swn * enh[nn * 64 + lane];
        ns += ue * nv;
        float n0 = item_emb[nn * 64 + lane];
        reg += n0 * n0;
    }
#pragma unroll
    for (int m = 32; m >= 1; m >>= 1) {
        ps += __shfl_xor(ps, m, 64);
        ns += __shfl_xor(ns, m, 64);
        reg += __shfl_xor(reg, m, 64);
    }
    if (lane == 0) {
        float x = ns * (1.f / N_NEGC) - ps;
        float sp = (x > 0.f) ? (x + log1pf(expf(-x))) : log1pf(expf(x));
        atomicAdd(&out[0], sp * (1.f / BATCHC));
        atomicAdd(&out[1], 0.5f * reg * (1.f / BATCHC));
    }
}

extern "C" void kernel_launch(void* const* d_in, const int* in_sizes, int n_in,
                              void* d_out, int out_size, void* d_ws, size_t ws_size,
                              hipStream_t stream) {
    const float* user_emb = (const float*)d_in[0];
    const float* item_emb = (const float*)d_in[1];
    const float* w0 = (const float*)d_in[2];
    const float* b0 = (const float*)d_in[3];
    const float* w2 = (const float*)d_in[4];
    const float* b2 = (const float*)d_in[5];
    const float* a_vals = (const float*)d_in[6];
    const float* s_vals = (const float*)d_in[7];
    const float* item_degree = (const float*)d_in[8];
    const int* a_rows = (const int*)d_in[9];
    const int* a_cols = (const int*)d_in[10];
    const int* s_rows = (const int*)d_in[11];
    const int* s_cols = (const int*)d_in[12];
    const int* tail_idx = (const int*)d_in[13];
    const int* head_idx = (const int*)d_in[14];
    const int* batch_user = (const int*)d_in[15];
    const int* batch_pos = (const int*)d_in[16];
    const int* batch_neg = (const int*)d_in[17];
    float* out = (float*)d_out;

    // ---- workspace carve (all 256B aligned) ----
    char* p = (char*)d_ws;
    auto carve = [&](size_t bytes) -> void* {
        void* r = (void*)p;
        p += (bytes + 255) & ~size_t(255);
        return r;
    };
    float* embA = (float*)carve((size_t)N_TOTALC * 64 * 4);
    float* embB = (float*)carve((size_t)N_TOTALC * 64 * 4);
    float* u1 = (float*)carve((size_t)N_USERC * 64 * 4);
    float* u2 = (float*)carve((size_t)N_USERC * 64 * 4);
    float* enh = (float*)carve((size_t)N_ITEMC * 64 * 4);
    float* tail_e = (float*)carve((size_t)N_TAILC * 64 * 4);
    float* top_e = (float*)carve((size_t)N_HEADC * 64 * 4);
    float* a_svals = (float*)carve((size_t)NNZ_AC * 4);
    int* a_scols = (int*)carve((size_t)NNZ_AC * 4);
    float* s_svals = (float*)carve((size_t)NNZ_SC * 4);
    int* s_scols = (int*)carve((size_t)NNZ_SC * 4);
    int* a_rowptr = (int*)carve((size_t)(N_TOTALC + 1) * 4);
    int* a_cursor = (int*)carve((size_t)N_TOTALC * 4);
    int* s_rowptr = (int*)carve((size_t)(N_USERC + 1) * 4);
    int* s_cursor = (int*)carve((size_t)N_USERC * 4);
    int* bsums = (int*)carve(128 * 4);
    int* ig_cols_buf = (int*)carve((size_t)N_TAILC * TOPKC * 4);
    float* ig_vals_buf = (float*)carve((size_t)N_TAILC * TOPKC * 4);
    float* Mrm = (float*)carve(64 * 64 * 4);
    float* cvec = (float*)carve(64 * 4);
    float* scores = (float*)carve((size_t)CHUNK_ROWS * N_HEADC * 4);

    // ---- CSR build for A (150000 rows, 2M nnz) ----
    hipMemsetAsync(a_cursor, 0, (size_t)N_TOTALC * 4, stream);
    hist_kernel<<<(NNZ_AC + 255) / 256, 256, 0, stream>>>(a_rows, NNZ_AC, a_cursor);
    {
        int nb = (N_TOTALC + 2047) / 2048;
        scan_p1<<<nb, 256, 0, stream>>>(a_cursor, N_TOTALC, a_rowptr, bsums);
        scan_p2<<<1, 64, 0, stream>>>(bsums, nb);
        scan_p3<<<(N_TOTALC + 255) / 256, 256, 0, stream>>>(a_rowptr, N_TOTALC, bsums, a_cursor, NNZ_AC);
    }
    scatter_kernel<<<(NNZ_AC + 255) / 256, 256, 0, stream>>>(a_vals, a_rows, a_cols, NNZ_AC, a_cursor, a_svals, a_scols);

    // ---- CSR build for S (100000 rows, 1M nnz) ----
    hipMemsetAsync(s_cursor, 0, (size_t)N_USERC * 4, stream);
    hist_kernel<<<(NNZ_SC + 255) / 256, 256, 0, stream>>>(s_rows, NNZ_SC, s_cursor);
    {
        int nb = (N_USERC + 2047) / 2048;
        scan_p1<<<nb, 256, 0, stream>>>(s_cursor, N_USERC, s_rowptr, bsums);
        scan_p2<<<1, 64, 0, stream>>>(bsums, nb);
        scan_p3<<<(N_USERC + 255) / 256, 256, 0, stream>>>(s_rowptr, N_USERC, bsums, s_cursor, NNZ_SC);
    }
    scatter_kernel<<<(NNZ_SC + 255) / 256, 256, 0, stream>>>(s_vals, s_rows, s_cols, NNZ_SC, s_cursor, s_svals, s_scols);

    // ---- collapsed encoder ----
    mc_kernel<<<17, 256, 0, stream>>>(w0, b0, w2, b2, Mrm, cvec);
    enc2_kernel<<<(N_TAILC + 3) / 4, 256, 0, stream>>>(item_emb, tail_idx, Mrm, cvec, tail_e, N_TAILC);
    enc2_kernel<<<(N_HEADC + 3) / 4, 256, 0, stream>>>(item_emb, head_idx, Mrm, cvec, top_e, N_HEADC);

    // ---- chunked scores GEMM + top-k ----
    for (int row0 = 0; row0 < N_TAILC; row0 += CHUNK_ROWS) {
        int m = N_TAILC - row0;
        if (m > CHUNK_ROWS) m = CHUNK_ROWS;
        int rb = (m + 127) / 128;
        score_gemm<<<dim3((N_HEADC + 127) / 128, rb), 256, 0, stream>>>(tail_e + (size_t)row0 * 64, top_e, scores, m);
        topk_rows<<<(m + 3) / 4, 256, 0, stream>>>(scores, m, row0, head_idx, ig_cols_buf, ig_vals_buf);
    }

    // ---- all_emb = concat(user_emb, item_emb); 3 A-layers ping-pong ----
    hipMemcpyAsync(embA, user_emb, (size_t)N_USERC * 64 * 4, hipMemcpyDeviceToDevice, stream);
    hipMemcpyAsync(embA + (size_t)N_USERC * 64, item_emb, (size_t)N_ITEMC * 64 * 4, hipMemcpyDeviceToDevice, stream);
    {
        int blocks = (N_TOTALC + 3) / 4;
        spmm_csr<<<blocks, 256, 0, stream>>>(a_rowptr, a_svals, a_scols, embA, embB, N_TOTALC);
        spmm_csr<<<blocks, 256, 0, stream>>>(a_rowptr, a_svals, a_scols, embB, embA, N_TOTALC);
        spmm_csr<<<blocks, 256, 0, stream>>>(a_rowptr, a_svals, a_scols, embA, embB, N_TOTALC);
    }
    const float* u0 = embB;
    const float* items = embB + (size_t)N_USERC * 64;

    // ---- 2 S-layers on users ----
    {
        int blocks = (N_USERC + 3) / 4;
        spmm_csr<<<blocks, 256, 0, stream>>>(s_rowptr, s_svals, s_scols, u0, u1, N_USERC);
        spmm_csr<<<blocks, 256, 0, stream>>>(s_rowptr, s_svals, s_scols, u1, u2, N_USERC);
    }

    // ---- item enhancement ----
    hipMemsetAsync(enh, 0, (size_t)N_ITEMC * 64 * 4, stream);
    ig_spmm_kernel<<<(N_TAILC * TOPKC) / 4, 256, 0, stream>>>(tail_idx, ig_cols_buf, ig_vals_buf, items, enh);

    // ---- loss + reg ----
    hipMemsetAsync(out, 0, 2 * sizeof(float), stream);
    loss_kernel<<<BATCHC / 4, 256, 0, stream>>>(u0, u1, u2, items, enh, item_degree,
                                                user_emb, item_emb, batch_user, batch_pos, batch_neg, out);
}

// Round 3
// 1385.756 us; speedup vs baseline: 1.1085x; 1.0308x over previous
//
#include <hip/hip_runtime.h>

#define N_USERC 100000
#define N_ITEMC 50000
#define N_TOTALC 150000
#define DC 64
#define NNZ_AC 2000000
#define NNZ_SC 1000000
#define N_TAILC 10000
#define N_HEADC 4000
#define TOPKC 10
#define BATCHC 4096
#define N_NEGC 4
#define CONVF 40.0f
#define CHUNK_ROWS 2500

#define NBA ((N_TOTALC + 2047) / 2048)   // 74
#define NBS ((N_USERC + 2047) / 2048)    // 49

// ---------------- fused histogram (A then S) ----------------
__global__ void hist_fused(const int* __restrict__ a_rows, const int* __restrict__ s_rows,
                           int* __restrict__ a_cnt, int* __restrict__ s_cnt) {
    int i = blockIdx.x * blockDim.x + threadIdx.x;
    if (i < NNZ_AC) {
        atomicAdd(&a_cnt[a_rows[i]], 1);
    } else {
        int j = i - NNZ_AC;
        if (j < NNZ_SC) atomicAdd(&s_cnt[s_rows[j]], 1);
    }
}

// ---------------- fused scan phase 1: 2048 elems/block ----------------
__global__ __launch_bounds__(256) void scan_p1_fused(const int* __restrict__ aIn, int* __restrict__ aOut,
                                                     const int* __restrict__ sIn, int* __restrict__ sOut,
                                                     int* __restrict__ bsums) {
    __shared__ int lds[256];
    int b = blockIdx.x;
    const int* in; int* out; int* bs; int n; int bb;
    if (b < NBA) { in = aIn; out = aOut; bs = bsums;       n = N_TOTALC; bb = b; }
    else         { in = sIn; out = sOut; bs = bsums + 128; n = N_USERC;  bb = b - NBA; }
    int tid = threadIdx.x;
    int base = bb * 2048 + tid * 8;
    int v[8];
    int s = 0;
#pragma unroll
    for (int k = 0; k < 8; ++k) {
        int idx = base + k;
        v[k] = s;
        s += (idx < n) ? in[idx] : 0;
    }
    lds[tid] = s;
    __syncthreads();
    for (int off = 1; off < 256; off <<= 1) {
        int t = (tid >= off) ? lds[tid - off] : 0;
        __syncthreads();
        lds[tid] += t;
        __syncthreads();
    }
    int texcl = (tid > 0) ? lds[tid - 1] : 0;
#pragma unroll
    for (int k = 0; k < 8; ++k) {
        int idx = base + k;
        if (idx < n) out[idx] = texcl + v[k];
    }
    if (tid == 255) bs[bb] = lds[255];
}

__global__ void scan_p2_fused(int* __restrict__ bsums) {
    if (threadIdx.x == 0 && blockIdx.x == 0) {
        int s = 0;
        for (int i = 0; i < NBA; ++i) { int t = bsums[i]; bsums[i] = s; s += t; }
        s = 0;
        for (int i = 0; i < NBS; ++i) { int t = bsums[128 + i]; bsums[128 + i] = s; s += t; }
    }
}

__global__ void scan_p3_fused(int* __restrict__ aOut, int* __restrict__ aCur,
                              int* __restrict__ sOut, int* __restrict__ sCur,
                              const int* __restrict__ bsums) {
    int i = blockIdx.x * blockDim.x + threadIdx.x;
    if (i < N_TOTALC) {
        int val = aOut[i] + bsums[i >> 11];
        aOut[i] = val;
        aCur[i] = val;
        if (i == 0) aOut[N_TOTALC] = NNZ_AC;
    } else {
        int j = i - N_TOTALC;
        if (j < N_USERC) {
            int val = sOut[j] + bsums[128 + (j >> 11)];
            sOut[j] = val;
            sCur[j] = val;
            if (j == 0) sOut[N_USERC] = NNZ_SC;
        }
    }
}

// ---------------- fused scatter: packed 8B (val,col) entries ----------------
__global__ void scatter_fused(const float* __restrict__ a_vals, const int* __restrict__ a_rows, const int* __restrict__ a_cols,
                              const float* __restrict__ s_vals, const int* __restrict__ s_rows, const int* __restrict__ s_cols,
                              int* __restrict__ aCur, int* __restrict__ sCur,
                              int2* __restrict__ aPack, int2* __restrict__ sPack) {
    int i = blockIdx.x * blockDim.x + threadIdx.x;
    if (i < NNZ_AC) {
        int p = atomicAdd(&aCur[a_rows[i]], 1);
        aPack[p] = make_int2(__float_as_int(a_vals[i]), a_cols[i]);
    } else {
        int j = i - NNZ_AC;
        if (j < NNZ_SC) {
            int p = atomicAdd(&sCur[s_rows[j]], 1);
            sPack[p] = make_int2(__float_as_int(s_vals[j]), s_cols[j]);
        }
    }
}

// ---------------- CSR SpMM (packed): one wave per row, lane = feature dim ----------------
__global__ __launch_bounds__(256) void spmm_csr(const int* __restrict__ rowptr,
                                                const int2* __restrict__ pack,
                                                const float* __restrict__ x,
                                                float* __restrict__ y, int nrows) {
    int w = (blockIdx.x * blockDim.x + threadIdx.x) >> 6;
    int lane = threadIdx.x & 63;
    if (w >= nrows) return;
    int s = rowptr[w], e = rowptr[w + 1];
    float a0 = 0.f, a1 = 0.f, a2 = 0.f, a3 = 0.f;
    int j = s;
    for (; j + 4 <= e; j += 4) {
        int2 e0 = pack[j], e1 = pack[j + 1], e2 = pack[j + 2], e3 = pack[j + 3];
        a0 += __int_as_float(e0.x) * x[(size_t)e0.y * 64 + lane];
        a1 += __int_as_float(e1.x) * x[(size_t)e1.y * 64 + lane];
        a2 += __int_as_float(e2.x) * x[(size_t)e2.y * 64 + lane];
        a3 += __int_as_float(e3.x) * x[(size_t)e3.y * 64 + lane];
    }
    for (; j < e; ++j) {
        int2 e0 = pack[j];
        a0 += __int_as_float(e0.x) * x[(size_t)e0.y * 64 + lane];
    }
    y[(size_t)w * 64 + lane] = a0 + a1 + a2 + a3;
}

// first A-layer: reads the virtual concat [user_emb; item_emb] directly
__global__ __launch_bounds__(256) void spmm_csr_concat(const int* __restrict__ rowptr,
                                                       const int2* __restrict__ pack,
                                                       const float* __restrict__ xu,
                                                       const float* __restrict__ xi,
                                                       float* __restrict__ y, int nrows) {
    int w = (blockIdx.x * blockDim.x + threadIdx.x) >> 6;
    int lane = threadIdx.x & 63;
    if (w >= nrows) return;
    int s = rowptr[w], e = rowptr[w + 1];
    float a0 = 0.f, a1 = 0.f, a2 = 0.f, a3 = 0.f;
    int j = s;
#define GATHER(c) ((c) < N_USERC ? xu[(size_t)(c) * 64 + lane] : xi[(size_t)((c) - N_USERC) * 64 + lane])
    for (; j + 4 <= e; j += 4) {
        int2 e0 = pack[j], e1 = pack[j + 1], e2 = pack[j + 2], e3 = pack[j + 3];
        a0 += __int_as_float(e0.x) * GATHER(e0.y);
        a1 += __int_as_float(e1.x) * GATHER(e1.y);
        a2 += __int_as_float(e2.x) * GATHER(e2.y);
        a3 += __int_as_float(e3.x) * GATHER(e3.y);
    }
    for (; j < e; ++j) {
        int2 e0 = pack[j];
        a0 += __int_as_float(e0.x) * GATHER(e0.y);
    }
#undef GATHER
    y[(size_t)w * 64 + lane] = a0 + a1 + a2 + a3;
}

// ---------------- collapsed encoder ----------------
__global__ __launch_bounds__(256) void mc_kernel(const float* __restrict__ w0, const float* __restrict__ b0,
                                                 const float* __restrict__ w2, const float* __restrict__ b2,
                                                 float* __restrict__ Mrm, float* __restrict__ cvec) {
    int idx = blockIdx.x * 256 + threadIdx.x;
    if (idx < 4096) {
        int j = idx >> 6, d = idx & 63;
        float acc = 0.f;
        for (int k = 0; k < 256; ++k) acc += w2[j * 256 + k] * w0[k * 64 + d];
        Mrm[idx] = acc;
    } else if (idx < 4160) {
        int i = idx - 4096;
        float acc = b2[i];
        for (int k = 0; k < 256; ++k) acc += w2[i * 256 + k] * b0[k];
        cvec[i] = acc;
    }
}

// enc(f) = f @ Mrm^T + cvec ; one wave per row; fused tail+head
__global__ __launch_bounds__(256) void enc2_fused(const float* __restrict__ emb,
                                                  const int* __restrict__ tail_idx, const int* __restrict__ head_idx,
                                                  const float* __restrict__ Mrm, const float* __restrict__ cvec,
                                                  float* __restrict__ tail_e, float* __restrict__ top_e) {
    __shared__ float fsh[4][64];
    int wv = threadIdx.x >> 6, lane = threadIdx.x & 63;
    int r = blockIdx.x * 4 + wv;
    int item;
    float* outp;
    if (r < N_TAILC) { item = tail_idx[r]; outp = tail_e + (size_t)r * 64; }
    else if (r < N_TAILC + N_HEADC) { item = head_idx[r - N_TAILC]; outp = top_e + (size_t)(r - N_TAILC) * 64; }
    else { item = -1; outp = nullptr; }
    if (item >= 0) fsh[wv][lane] = emb[(size_t)item * 64 + lane];
    __syncthreads();
    if (item < 0) return;
    float acc = cvec[lane];
#pragma unroll
    for (int d4 = 0; d4 < 64; d4 += 4) {
        float4 m4 = *(const float4*)&Mrm[lane * 64 + d4];
        float4 f4 = *(const float4*)&fsh[wv][d4];
        acc += m4.x * f4.x + m4.y * f4.y + m4.z * f4.z + m4.w * f4.w;
    }
    outp[lane] = acc;
}

// ---------------- score GEMM: C[m x 4000] = A[m x 64] @ B[4000 x 64]^T ----------------
__global__ __launch_bounds__(256) void score_gemm(const float* __restrict__ A,
                                                  const float* __restrict__ B,
                                                  float* __restrict__ C, int M) {
    __shared__ float As[32][132];
    __shared__ float Bs[32][132];
    int tid = threadIdx.x;
    int tx = tid & 15, ty = tid >> 4;
    int rowbase = blockIdx.y * 128;
    int colbase = blockIdx.x * 128;
    float acc[8][8];
#pragma unroll
    for (int i = 0; i < 8; ++i)
#pragma unroll
        for (int j = 0; j < 8; ++j) acc[i][j] = 0.f;

    for (int k0 = 0; k0 < 64; k0 += 32) {
        __syncthreads();
#pragma unroll
        for (int i = 0; i < 4; ++i) {
            int f = tid + i * 256;
            int r = f >> 3;
            int kq = (f & 7) << 2;
            int grow = rowbase + r;
            float4 av = (grow < M) ? *(const float4*)&A[(size_t)grow * 64 + k0 + kq]
                                   : make_float4(0.f, 0.f, 0.f, 0.f);
            As[kq + 0][r] = av.x; As[kq + 1][r] = av.y; As[kq + 2][r] = av.z; As[kq + 3][r] = av.w;
            int gcol = colbase + r;
            float4 bv = (gcol < N_HEADC) ? *(const float4*)&B[(size_t)gcol * 64 + k0 + kq]
                                         : make_float4(0.f, 0.f, 0.f, 0.f);
            Bs[kq + 0][r] = bv.x; Bs[kq + 1][r] = bv.y; Bs[kq + 2][r] = bv.z; Bs[kq + 3][r] = bv.w;
        }
        __syncthreads();
#pragma unroll
        for (int k = 0; k < 32; ++k) {
            float a[8], b[8];
#pragma unroll
            for (int i = 0; i < 8; ++i) a[i] = As[k][ty + 16 * i];
#pragma unroll
            for (int j = 0; j < 8; ++j) b[j] = Bs[k][tx + 16 * j];
#pragma unroll
            for (int i = 0; i < 8; ++i)
#pragma unroll
                for (int j = 0; j < 8; ++j) acc[i][j] += a[i] * b[j];
        }
    }
#pragma unroll
    for (int i = 0; i < 8; ++i) {
        int r = rowbase + ty + 16 * i;
        if (r < M) {
#pragma unroll
            for (int j = 0; j < 8; ++j) {
                int c = colbase + tx + 16 * j;
                if (c < N_HEADC) C[(size_t)r * N_HEADC + c] = acc[i][j];
            }
        }
    }
}

// ---------------- per-row top-k on materialized scores ----------------
__global__ __launch_bounds__(256) void topk_rows(const float* __restrict__ scores, int nrows, int row0,
                                                 const int* __restrict__ head_idx,
                                                 int* __restrict__ ig_cols, float* __restrict__ ig_vals) {
    int w = (blockIdx.x * blockDim.x + threadIdx.x) >> 6;
    int lane = threadIdx.x & 63;
    if (w >= nrows) return;
    const float* srow = scores + (size_t)w * N_HEADC;
    float v[TOPKC];
    int id[TOPKC];
#pragma unroll
    for (int k = 0; k < TOPKC; ++k) { v[k] = -1e30f; id[k] = -1; }
    for (int it = 0; it < 16; ++it) {
        int f4 = lane + it * 64;
        if (f4 < 1000) {
            float4 s4 = ((const float4*)srow)[f4];
            int cb = f4 * 4;
            float vv[4] = { s4.x, s4.y, s4.z, s4.w };
#pragma unroll
            for (int q = 0; q < 4; ++q) {
                float sc = vv[q];
                if (sc > v[TOPKC - 1]) {
                    float cv = sc; int ci = cb + q;
#pragma unroll
                    for (int k = 0; k < TOPKC; ++k) {
                        if (cv > v[k]) { float t = v[k]; int ti = id[k]; v[k] = cv; id[k] = ci; cv = t; ci = ti; }
                    }
                }
            }
        }
    }
    int ptr = 0;
    float ssum = 0.f;
    float outv = 0.f;
    int outid = -1;
#pragma unroll
    for (int r = 0; r < TOPKC; ++r) {
        float cv = (ptr < TOPKC) ? v[ptr] : -1e30f;
        int ci = (ptr < TOPKC) ? id[ptr] : -1;
        int wl = lane;
#pragma unroll
        for (int m = 1; m < 64; m <<= 1) {
            float ov = __shfl_xor(cv, m, 64);
            int oi = __shfl_xor(ci, m, 64);
            int ol = __shfl_xor(wl, m, 64);
            if (ov > cv || (ov == cv && ol < wl)) { cv = ov; ci = oi; wl = ol; }
        }
        if (wl == lane) ptr++;
        ssum += 1.f / (1.f + expf(-cv));
        if (lane == r) { outv = cv; outid = ci; }
    }
    if (lane < TOPKC) {
        float s = 1.f / (1.f + expf(-outv));
        float wgt = s / (ssum + 1.f);
        int grow = row0 + w;
        ig_vals[grow * TOPKC + lane] = wgt;
        ig_cols[grow * TOPKC + lane] = head_idx[outid];
    }
}

// ---------------- item_enh accumulation ----------------
__global__ __launch_bounds__(256) void ig_spmm_kernel(const int* __restrict__ tail_idx,
                                                      const int* __restrict__ ig_cols,
                                                      const float* __restrict__ ig_vals,
                                                      const float* __restrict__ items,
                                                      float* __restrict__ enh) {
    int e = (blockIdx.x * blockDim.x + threadIdx.x) >> 6;
    int lane = threadIdx.x & 63;
    if (e >= N_TAILC * TOPKC) return;
    int row = tail_idx[e / TOPKC];
    int col = ig_cols[e];
    float w = ig_vals[e];
    atomicAdd(&enh[(size_t)row * 64 + lane], w * items[(size_t)col * 64 + lane]);
}

// ---------------- final loss ----------------
__global__ __launch_bounds__(256) void loss_kernel(const float* __restrict__ u0, const float* __restrict__ u1,
                                                   const float* __restrict__ u2, const float* __restrict__ items,
                                                   const float* __restrict__ enh, const float* __restrict__ deg,
                                                   const float* __restrict__ user_emb, const float* __restrict__ item_emb,
                                                   const int* __restrict__ bu, const int* __restrict__ bp,
                                                   const int* __restrict__ bn, float* __restrict__ out) {
    int w = (blockIdx.x * blockDim.x + threadIdx.x) >> 6;
    int lane = threadIdx.x & 63;
    if (w >= BATCHC) return;
    int uu = bu[w], pp = bp[w];
    float ue = (u0[uu * 64 + lane] + u1[uu * 64 + lane] + u2[uu * 64 + lane]) * (1.f / 3.f);
    float swp = CONVF / (CONVF + expf(deg[pp] * (1.f / CONVF)));
    float pe = items[pp * 64 + lane] + swp * enh[pp * 64 + lane];
    float ps = ue * pe;
    float ns = 0.f;
    float u0e = user_emb[uu * 64 + lane];
    float p0e = item_emb[pp * 64 + lane];
    float reg = u0e * u0e + p0e * p0e;
#pragma unroll
    for (int k = 0; k < N_NEGC; ++k) {
        int nn = bn[w * N_NEGC + k];
        float swn = CONVF / (CONVF + expf(deg[nn] * (1.f / CONVF)));
        float nv = items[nn * 64 + lane] + swn * enh[nn * 64 + lane];
        ns += ue * nv;
        float n0 = item_emb[nn * 64 + lane];
        reg += n0 * n0;
    }
#pragma unroll
    for (int m = 32; m >= 1; m >>= 1) {
        ps += __shfl_xor(ps, m, 64);
        ns += __shfl_xor(ns, m, 64);
        reg += __shfl_xor(reg, m, 64);
    }
    if (lane == 0) {
        float x = ns * (1.f / N_NEGC) - ps;
        float sp = (x > 0.f) ? (x + log1pf(expf(-x))) : log1pf(expf(x));
        atomicAdd(&out[0], sp * (1.f / BATCHC));
        atomicAdd(&out[1], 0.5f * reg * (1.f / BATCHC));
    }
}

extern "C" void kernel_launch(void* const* d_in, const int* in_sizes, int n_in,
                              void* d_out, int out_size, void* d_ws, size_t ws_size,
                              hipStream_t stream) {
    const float* user_emb = (const float*)d_in[0];
    const float* item_emb = (const float*)d_in[1];
    const float* w0 = (const float*)d_in[2];
    const float* b0 = (const float*)d_in[3];
    const float* w2 = (const float*)d_in[4];
    const float* b2 = (const float*)d_in[5];
    const float* a_vals = (const float*)d_in[6];
    const float* s_vals = (const float*)d_in[7];
    const float* item_degree = (const float*)d_in[8];
    const int* a_rows = (const int*)d_in[9];
    const int* a_cols = (const int*)d_in[10];
    const int* s_rows = (const int*)d_in[11];
    const int* s_cols = (const int*)d_in[12];
    const int* tail_idx = (const int*)d_in[13];
    const int* head_idx = (const int*)d_in[14];
    const int* batch_user = (const int*)d_in[15];
    const int* batch_pos = (const int*)d_in[16];
    const int* batch_neg = (const int*)d_in[17];
    float* out = (float*)d_out;

    // ---- workspace carve ----
    char* p = (char*)d_ws;
    auto carve = [&](size_t bytes) -> void* {
        void* r = (void*)p;
        p += (bytes + 255) & ~size_t(255);
        return r;
    };
    float* embA = (float*)carve((size_t)N_TOTALC * 64 * 4);
    float* embB = (float*)carve((size_t)N_TOTALC * 64 * 4);
    float* u1 = (float*)carve((size_t)N_USERC * 64 * 4);
    float* u2 = (float*)carve((size_t)N_USERC * 64 * 4);
    float* enh = (float*)carve((size_t)N_ITEMC * 64 * 4);
    float* tail_e = (float*)carve((size_t)N_TAILC * 64 * 4);
    float* top_e = (float*)carve((size_t)N_HEADC * 64 * 4);
    int2* aPack = (int2*)carve((size_t)NNZ_AC * 8);
    int2* sPack = (int2*)carve((size_t)NNZ_SC * 8);
    int* a_rowptr = (int*)carve((size_t)(N_TOTALC + 1) * 4);
    int* a_cursor = (int*)carve((size_t)N_TOTALC * 4);
    int* s_rowptr = (int*)carve((size_t)(N_USERC + 1) * 4);
    int* s_cursor = (int*)carve((size_t)N_USERC * 4);
    int* bsums = (int*)carve(256 * 4);
    int* ig_cols_buf = (int*)carve((size_t)N_TAILC * TOPKC * 4);
    float* ig_vals_buf = (float*)carve((size_t)N_TAILC * TOPKC * 4);
    float* Mrm = (float*)carve(64 * 64 * 4);
    float* cvec = (float*)carve(64 * 4);
    float* scores = (float*)carve((size_t)CHUNK_ROWS * N_HEADC * 4);

    // ---- fused CSR build (A + S) ----
    hipMemsetAsync(a_cursor, 0, (size_t)N_TOTALC * 4, stream);
    hipMemsetAsync(s_cursor, 0, (size_t)N_USERC * 4, stream);
    hist_fused<<<(NNZ_AC + NNZ_SC + 255) / 256, 256, 0, stream>>>(a_rows, s_rows, a_cursor, s_cursor);
    scan_p1_fused<<<NBA + NBS, 256, 0, stream>>>(a_cursor, a_rowptr, s_cursor, s_rowptr, bsums);
    scan_p2_fused<<<1, 64, 0, stream>>>(bsums);
    scan_p3_fused<<<(N_TOTALC + N_USERC + 255) / 256, 256, 0, stream>>>(a_rowptr, a_cursor, s_rowptr, s_cursor, bsums);
    scatter_fused<<<(NNZ_AC + NNZ_SC + 255) / 256, 256, 0, stream>>>(a_vals, a_rows, a_cols,
                                                                     s_vals, s_rows, s_cols,
                                                                     a_cursor, s_cursor, aPack, sPack);

    // ---- collapsed encoder (tail + head fused) ----
    mc_kernel<<<17, 256, 0, stream>>>(w0, b0, w2, b2, Mrm, cvec);
    enc2_fused<<<(N_TAILC + N_HEADC + 3) / 4, 256, 0, stream>>>(item_emb, tail_idx, head_idx, Mrm, cvec, tail_e, top_e);

    // ---- chunked scores GEMM + top-k ----
    for (int row0 = 0; row0 < N_TAILC; row0 += CHUNK_ROWS) {
        int m = N_TAILC - row0;
        if (m > CHUNK_ROWS) m = CHUNK_ROWS;
        int rb = (m + 127) / 128;
        score_gemm<<<dim3((N_HEADC + 127) / 128, rb), 256, 0, stream>>>(tail_e + (size_t)row0 * 64, top_e, scores, m);
        topk_rows<<<(m + 3) / 4, 256, 0, stream>>>(scores, m, row0, head_idx, ig_cols_buf, ig_vals_buf);
    }

    // ---- 3 A-layers (first reads inputs directly, then ping-pong) ----
    {
        int blocks = (N_TOTALC + 3) / 4;
        spmm_csr_concat<<<blocks, 256, 0, stream>>>(a_rowptr, aPack, user_emb, item_emb, embB, N_TOTALC);
        spmm_csr<<<blocks, 256, 0, stream>>>(a_rowptr, aPack, embB, embA, N_TOTALC);
        spmm_csr<<<blocks, 256, 0, stream>>>(a_rowptr, aPack, embA, embB, N_TOTALC);
    }
    const float* u0 = embB;
    const float* items = embB + (size_t)N_USERC * 64;

    // ---- 2 S-layers on users ----
    {
        int blocks = (N_USERC + 3) / 4;
        spmm_csr<<<blocks, 256, 0, stream>>>(s_rowptr, sPack, u0, u1, N_USERC);
        spmm_csr<<<blocks, 256, 0, stream>>>(s_rowptr, sPack, u1, u2, N_USERC);
    }

    // ---- item enhancement ----
    hipMemsetAsync(enh, 0, (size_t)N_ITEMC * 64 * 4, stream);
    ig_spmm_kernel<<<(N_TAILC * TOPKC) / 4, 256, 0, stream>>>(tail_idx, ig_cols_buf, ig_vals_buf, items, enh);

    // ---- loss + reg ----
    hipMemsetAsync(out, 0, 2 * sizeof(float), stream);
    loss_kernel<<<BATCHC / 4, 256, 0, stream>>>(u0, u1, u2, items, enh, item_degree,
                                                user_emb, item_emb, batch_user, batch_pos, batch_neg, out);
}